// Round 9
// baseline (62.988 us; speedup 1.0000x reference)
//
#include <hip/hip_runtime.h>
#include <hip/hip_bf16.h>
#include <math.h>

#define DDIM 200
#define D4   50
#define CCH  50
#define NREL 237
#define MAXE 16          // elements per GEMM chunk
#define NT   256
#define KT   7           // K tiles of 32 -> 224 (200 real, zero-padded)
#define KTKG 28          // (kt,kg) pairs: k0 = ktkg*8
#define NCOLP 208        // padded col count in packed W
#define ZSTR 208         // Z row stride (bf16)
#define PACK_UNITS (NREL * KTKG * NCOLP)   // 1,380,288
#define EPB_EPI 8        // elements per epilogue block (2 per wave)

typedef __attribute__((ext_vector_type(8))) short bf16x8;
typedef __attribute__((ext_vector_type(4))) float f32x4;

__device__ __forceinline__ uint f2bf(float x) {
    __hip_bfloat16 h = __float2bfloat16(x);   // RNE
    return (uint)*reinterpret_cast<ushort*>(&h);
}
__device__ __forceinline__ float bf2f(ushort u) {
    return __uint_as_float((uint)u << 16);
}
__device__ __forceinline__ float fast_tanh(float x) {
    const float xc = fminf(fmaxf(x, -20.f), 20.f);
    const float e  = __expf(2.f * xc);
    return 1.f - __fdividef(2.f, e + 1.f);
}

// ---------- Kernel 1: block 0 = sort + chunk + per-position tables; rest = W pack ----------
__global__ __launch_bounds__(1024) void prep_kernel(
    const float* __restrict__ W, ushort* __restrict__ Wpk, int do_pack,
    const int* __restrict__ bi, int B, int nblk,
    int* __restrict__ perm, int* __restrict__ blk_r,
    int* __restrict__ blk_start, int* __restrict__ blk_cnt,
    int* __restrict__ eidArr, int* __restrict__ prb, int* __restrict__ prr)
{
    const int tid = threadIdx.x;

    if (blockIdx.x != 0) {
        if (!do_pack) return;
        const int u = (blockIdx.x - 1) * 1024 + tid;
        if (u >= PACK_UNITS) return;
        const int col  = u % NCOLP;
        const int rk   = u / NCOLP;
        const int ktkg = rk % KTKG;
        const int r    = rk / KTKG;
        const int k0   = ktkg * 8;
        uint4 pk = {0u, 0u, 0u, 0u};
        if (col < DDIM) {
            const float* base = W + (size_t)r * DDIM * DDIM + col;
            uint vv[8];
            #pragma unroll
            for (int j = 0; j < 8; ++j) {
                const int k = k0 + j;
                vv[j] = (k < DDIM) ? f2bf(base[(size_t)k * DDIM]) : 0u;  // coalesced per j
            }
            pk.x = vv[0] | (vv[1] << 16);
            pk.y = vv[2] | (vv[3] << 16);
            pk.z = vv[4] | (vv[5] << 16);
            pk.w = vv[6] | (vv[7] << 16);
        }
        *(uint4*)&Wpk[(size_t)u * 8] = pk;
        return;
    }

    // ---- block 0: counting sort + balanced chunk emission + tables ----
    __shared__ int hist[NREL];
    __shared__ int offs[NREL];
    __shared__ int wsum[16], wsum2[16];
    const int lane = tid & 63;
    const int w    = tid >> 6;

    if (tid < NREL) hist[tid] = 0;
    __syncthreads();
    for (int i = tid; i < B; i += 1024)
        atomicAdd(&hist[bi[i * 3 + 1]], 1);
    __syncthreads();

    const int v  = (tid < NREL) ? hist[tid] : 0;
    const int v2 = (tid < NREL) ? (v + MAXE - 1) / MAXE : 0;
    int s = v, s2 = v2;
    #pragma unroll
    for (int off = 1; off < 64; off <<= 1) {
        const int u  = __shfl_up(s,  off, 64);
        const int u2 = __shfl_up(s2, off, 64);
        if (lane >= off) { s += u; s2 += u2; }
    }
    if (lane == 63) { wsum[w] = s; wsum2[w] = s2; }
    __syncthreads();
    int base = 0, base2 = 0;
    for (int i = 0; i < w; ++i) { base += wsum[i]; base2 += wsum2[i]; }
    const int my_off  = base  + s  - v;
    const int my_boff = base2 + s2 - v2;
    if (tid < NREL) offs[tid] = my_off;
    __syncthreads();

    for (int i = tid; i < nblk; i += 1024) blk_cnt[i] = 0;
    if (tid < NREL && v > 0) {
        const int nb = (v + MAXE - 1) / MAXE;
        const int cb = v / nb, ext = v - cb * nb;
        int pos = my_off;
        for (int j = 0; j < nb; ++j) {
            const int c = cb + (j < ext ? 1 : 0);
            blk_r[my_boff + j]     = tid;
            blk_start[my_boff + j] = pos;
            blk_cnt[my_boff + j]   = c;
            pos += c;
        }
    }
    __syncthreads();
    for (int i = tid; i < B; i += 1024) {
        const int pos = atomicAdd(&offs[bi[i * 3 + 1]], 1);
        perm[pos] = i;
    }
    __syncthreads();
    // per-sorted-position tables for GEMM (eid) and epilogue (b, r)
    for (int p = tid; p < B; p += 1024) {
        const int b = perm[p];
        eidArr[2 * p]     = bi[3 * b + 0];
        eidArr[2 * p + 1] = bi[3 * b + 2];
        prb[p] = b;
        prr[p] = bi[3 * b + 1];
    }
}

// ---------- Kernel 2: barrier-free, LDS-free MFMA GEMM -> Z (bf16 tanh'd se/te) ----------
template <bool PACKED>
__global__ __launch_bounds__(NT) void gemm_kernel(
    const float*  __restrict__ ent,
    const float*  __restrict__ W,
    const ushort* __restrict__ Wpk,
    const int*    __restrict__ blk_r,
    const int*    __restrict__ blk_start,
    const int*    __restrict__ blk_cnt,
    const int*    __restrict__ eidArr,
    int nblk,
    ushort*       __restrict__ Zpk)
{
    const int tid  = threadIdx.x;
    const int w    = tid >> 6;
    const int lane = tid & 63;
    const int l16  = lane & 15;
    const int kg   = lane >> 4;

    // bijective XCD-chunked swizzle (same-relation chunks share an XCD L2)
    const int bid = blockIdx.x;
    const int q = nblk >> 3, rmd = nblk & 7;
    const int xcd = bid & 7, idx = bid >> 3;
    const int gidx = (xcd < rmd ? xcd * (q + 1) : rmd * (q + 1) + (xcd - rmd) * q) + idx;

    const int cnt = blk_cnt[gidx];
    if (cnt == 0) return;
    const int r     = blk_r[gidx];
    const int start = blk_start[gidx];
    const int rows  = 2 * cnt;

    const int row0 = l16, row1 = 16 + l16;
    const int e0 = (row0 < rows) ? eidArr[2 * start + row0] : 0;
    const int e1 = (row1 < rows) ? eidArr[2 * start + row1] : 0;
    const float* __restrict__ xp0 = ent + (size_t)e0 * DDIM;
    const float* __restrict__ xp1 = ent + (size_t)e1 * DDIM;

    const ushort* __restrict__ Wp = Wpk + (size_t)r * KTKG * NCOLP * 8;
    const float*  __restrict__ Wr = W + (size_t)r * DDIM * DDIM;
    const int nslots = (w == 0) ? 4 : 3;

    f32x4 acc[2][4];
    #pragma unroll
    for (int mt = 0; mt < 2; ++mt)
        #pragma unroll
        for (int s = 0; s < 4; ++s)
            acc[mt][s] = (f32x4){0.f, 0.f, 0.f, 0.f};

    #pragma unroll 2
    for (int kt = 0; kt < KT; ++kt) {
        const int ktkg = kt * 4 + kg;
        const int k0   = ktkg * 8;
        // A fragments straight from global (each row byte read exactly once overall)
        uint4 pa0 = {0u, 0u, 0u, 0u}, pa1 = {0u, 0u, 0u, 0u};
        if (ktkg < 25) {
            const float4 a = *(const float4*)(xp0 + k0);
            const float4 b = *(const float4*)(xp0 + k0 + 4);
            pa0.x = f2bf(a.x) | (f2bf(a.y) << 16);
            pa0.y = f2bf(a.z) | (f2bf(a.w) << 16);
            pa0.z = f2bf(b.x) | (f2bf(b.y) << 16);
            pa0.w = f2bf(b.z) | (f2bf(b.w) << 16);
            const float4 c = *(const float4*)(xp1 + k0);
            const float4 d = *(const float4*)(xp1 + k0 + 4);
            pa1.x = f2bf(c.x) | (f2bf(c.y) << 16);
            pa1.y = f2bf(c.z) | (f2bf(c.w) << 16);
            pa1.z = f2bf(d.x) | (f2bf(d.y) << 16);
            pa1.w = f2bf(d.z) | (f2bf(d.w) << 16);
        }
        const bf16x8 a0 = *reinterpret_cast<const bf16x8*>(&pa0);
        const bf16x8 a1 = *reinterpret_cast<const bf16x8*>(&pa1);
        #pragma unroll
        for (int s = 0; s < 4; ++s) {
            if (s < nslots) {
                const int col = (w + 4 * s) * 16 + l16;
                bf16x8 bfr;
                if (PACKED) {
                    bfr = *(const bf16x8*)&Wp[((size_t)ktkg * NCOLP + col) * 8];
                } else {
                    #pragma unroll
                    for (int j = 0; j < 8; ++j) {
                        const int k = k0 + j;
                        const float vv = (k < DDIM && col < DDIM) ? Wr[k * DDIM + col] : 0.f;
                        bfr[j] = (short)f2bf(vv);
                    }
                }
                acc[0][s] = __builtin_amdgcn_mfma_f32_16x16x32_bf16(a0, bfr, acc[0][s], 0, 0, 0);
                acc[1][s] = __builtin_amdgcn_mfma_f32_16x16x32_bf16(a1, bfr, acc[1][s], 0, 0, 0);
            }
        }
    }

    // tanh + bf16 Z write: D row=kg*4+v (+16*mt), col=l16 (+16*(w+4s))
    #pragma unroll
    for (int mt = 0; mt < 2; ++mt) {
        #pragma unroll
        for (int s = 0; s < 4; ++s) {
            if (s < nslots) {
                const int col = (w + 4 * s) * 16 + l16;
                #pragma unroll
                for (int v = 0; v < 4; ++v) {
                    const int grow = 16 * mt + kg * 4 + v;
                    if (grow < rows)
                        Zpk[(size_t)(2 * start + grow) * ZSTR + col] =
                            (ushort)f2bf(fast_tanh(acc[mt][s][v]));
                }
            }
        }
    }
}

// ---------- Kernel 3: streaming fused conv+relu+fc epilogue ----------
__global__ __launch_bounds__(NT) void epi_kernel(
    const ushort* __restrict__ Zpk,
    const float*  __restrict__ rel_emb,
    const float*  __restrict__ conv_w,
    const float*  __restrict__ conv_b,
    const float*  __restrict__ fc_w,
    const float*  __restrict__ fc_b,
    const int*    __restrict__ prb,
    const int*    __restrict__ prr,
    int B,
    float*        __restrict__ out)
{
    __shared__ __align__(16) float4 fsh[CCH * D4];   // fc_w, 40 KB
    __shared__ __align__(16) float  cwb[CCH][4];     // {w0,w1,w2,b}

    const int tid  = threadIdx.x;
    const int w    = tid >> 6;
    const int lane = tid & 63;

    for (int i = tid; i < CCH * D4; i += NT) fsh[i] = ((const float4*)fc_w)[i];
    if (tid < CCH) {
        cwb[tid][0] = conv_w[tid * 3 + 0];
        cwb[tid][1] = conv_w[tid * 3 + 1];
        cwb[tid][2] = conv_w[tid * 3 + 2];
        cwb[tid][3] = conv_b[tid];
    }
    __syncthreads();

    const int p0 = blockIdx.x * EPB_EPI + w * 2;
    const int p1 = p0 + 1;
    const bool l0 = (p0 < B), l1 = (p1 < B);
    const int b0 = l0 ? prb[p0] : 0;
    const int b1 = l1 ? prb[p1] : 0;
    const int r0 = l0 ? prr[p0] : 0;
    const int r1 = l1 ? prr[p1] : 0;

    float4 a0 = {0.f, 0.f, 0.f, 0.f}, a1 = {0.f, 0.f, 0.f, 0.f};
    if (lane < D4) {
        float4 se0 = {0,0,0,0}, te0 = {0,0,0,0}, rv0 = {0,0,0,0};
        float4 se1 = {0,0,0,0}, te1 = {0,0,0,0}, rv1 = {0,0,0,0};
        if (l0) {
            rv0 = *(const float4*)&rel_emb[r0 * DDIM + 4 * lane];
            const ushort4 su = *(const ushort4*)&Zpk[(size_t)(2 * p0) * ZSTR + 4 * lane];
            const ushort4 tu = *(const ushort4*)&Zpk[(size_t)(2 * p0 + 1) * ZSTR + 4 * lane];
            se0 = (float4){bf2f(su.x), bf2f(su.y), bf2f(su.z), bf2f(su.w)};
            te0 = (float4){bf2f(tu.x), bf2f(tu.y), bf2f(tu.z), bf2f(tu.w)};
        }
        if (l1) {
            rv1 = *(const float4*)&rel_emb[r1 * DDIM + 4 * lane];
            const ushort4 su = *(const ushort4*)&Zpk[(size_t)(2 * p1) * ZSTR + 4 * lane];
            const ushort4 tu = *(const ushort4*)&Zpk[(size_t)(2 * p1 + 1) * ZSTR + 4 * lane];
            se1 = (float4){bf2f(su.x), bf2f(su.y), bf2f(su.z), bf2f(su.w)};
            te1 = (float4){bf2f(tu.x), bf2f(tu.y), bf2f(tu.z), bf2f(tu.w)};
        }
        for (int c = 0; c < CCH; ++c) {
            const float4 cw = *(const float4*)&cwb[c][0];     // LDS broadcast
            const float4 f4 = fsh[c * D4 + lane];             // reused across both elems
            {
                const float v0 = fmaf(cw.x, se0.x, fmaf(cw.y, rv0.x, fmaf(cw.z, te0.x, cw.w)));
                const float v1 = fmaf(cw.x, se0.y, fmaf(cw.y, rv0.y, fmaf(cw.z, te0.y, cw.w)));
                const float v2 = fmaf(cw.x, se0.z, fmaf(cw.y, rv0.z, fmaf(cw.z, te0.z, cw.w)));
                const float v3 = fmaf(cw.x, se0.w, fmaf(cw.y, rv0.w, fmaf(cw.z, te0.w, cw.w)));
                a0.x = fmaf(fmaxf(v0, 0.f), f4.x, a0.x);
                a0.y = fmaf(fmaxf(v1, 0.f), f4.y, a0.y);
                a0.z = fmaf(fmaxf(v2, 0.f), f4.z, a0.z);
                a0.w = fmaf(fmaxf(v3, 0.f), f4.w, a0.w);
            }
            {
                const float v0 = fmaf(cw.x, se1.x, fmaf(cw.y, rv1.x, fmaf(cw.z, te1.x, cw.w)));
                const float v1 = fmaf(cw.x, se1.y, fmaf(cw.y, rv1.y, fmaf(cw.z, te1.y, cw.w)));
                const float v2 = fmaf(cw.x, se1.z, fmaf(cw.y, rv1.z, fmaf(cw.z, te1.z, cw.w)));
                const float v3 = fmaf(cw.x, se1.w, fmaf(cw.y, rv1.w, fmaf(cw.z, te1.w, cw.w)));
                a1.x = fmaf(fmaxf(v0, 0.f), f4.x, a1.x);
                a1.y = fmaf(fmaxf(v1, 0.f), f4.y, a1.y);
                a1.z = fmaf(fmaxf(v2, 0.f), f4.z, a1.z);
                a1.w = fmaf(fmaxf(v3, 0.f), f4.w, a1.w);
            }
        }
    }
    float s0 = (a0.x + a0.y) + (a0.z + a0.w);
    float s1 = (a1.x + a1.y) + (a1.z + a1.w);
    #pragma unroll
    for (int off = 32; off; off >>= 1) {
        s0 += __shfl_down(s0, off, 64);
        s1 += __shfl_down(s1, off, 64);
    }
    if (lane == 0) {
        const float fb = fc_b[0];
        if (l0) out[b0] = s0 + fb;
        if (l1) out[b1] = s1 + fb;
    }
}

extern "C" void kernel_launch(void* const* d_in, const int* in_sizes, int n_in,
                              void* d_out, int out_size, void* d_ws, size_t ws_size,
                              hipStream_t stream) {
    const int*   bi      = (const int*)  d_in[0];
    const float* ent     = (const float*)d_in[1];
    const float* rel_emb = (const float*)d_in[2];
    const float* W       = (const float*)d_in[3];
    const float* conv_w  = (const float*)d_in[4];
    const float* conv_b  = (const float*)d_in[5];
    const float* fc_w    = (const float*)d_in[6];
    const float* fc_b    = (const float*)d_in[7];
    float*       out     = (float*)d_out;

    const int B    = in_sizes[0] / 3;                  // 8192
    const int nblk = NREL + (B + MAXE - 1) / MAXE;     // 749 worst-case chunks

    int* perm      = (int*)d_ws;                       // B
    int* blk_r     = perm + B;                         // nblk
    int* blk_start = blk_r + nblk;                     // nblk
    int* blk_cnt   = blk_start + nblk;                 // nblk
    int* eidArr    = blk_cnt + nblk;                   // 2B
    int* prb       = eidArr + 2 * B;                   // B
    int* prr       = prb + B;                          // B

    const size_t meta_bytes = (size_t)(5 * B + 3 * nblk) * sizeof(int);
    const size_t z_off      = (meta_bytes + 255) & ~(size_t)255;
    const size_t z_bytes    = (size_t)2 * B * ZSTR * sizeof(ushort);
    const size_t pk_off     = (z_off + z_bytes + 255) & ~(size_t)255;
    const size_t need       = pk_off + (size_t)PACK_UNITS * 16;
    const bool   use_packed = (ws_size >= need);
    ushort* Zpk = (ushort*)((char*)d_ws + z_off);
    ushort* Wpk = (ushort*)((char*)d_ws + pk_off);

    const int prep_blocks = 1 + (PACK_UNITS + 1023) / 1024;
    prep_kernel<<<prep_blocks, 1024, 0, stream>>>(
        W, Wpk, use_packed ? 1 : 0, bi, B, nblk,
        perm, blk_r, blk_start, blk_cnt, eidArr, prb, prr);

    if (use_packed) {
        gemm_kernel<true><<<nblk, NT, 0, stream>>>(
            ent, W, Wpk, blk_r, blk_start, blk_cnt, eidArr, nblk, Zpk);
    } else {
        gemm_kernel<false><<<nblk, NT, 0, stream>>>(
            ent, W, Wpk, blk_r, blk_start, blk_cnt, eidArr, nblk, Zpk);
    }

    epi_kernel<<<(B + EPB_EPI - 1) / EPB_EPI, NT, 0, stream>>>(
        Zpk, rel_emb, conv_w, conv_b, fc_w, fc_b, prb, prr, B, out);
}

// Round 10
// 58.501 us; speedup vs baseline: 1.0767x; 1.0767x over previous
//
#include <hip/hip_runtime.h>
#include <hip/hip_bf16.h>
#include <math.h>

#define DDIM 200
#define D4   50
#define CCH  50
#define NREL 237
#define MAXE 8           // elements per chunk
#define AROWS 16         // M-tile rows = 2*MAXE
#define NT   256
#define KT   7           // K tiles of 32 -> 224 (200 real, zero-padded)
#define KTKG 28          // (kt,kg) pairs: k0 = ktkg*8
#define NCOLP 208        // padded col count in packed W
#define OSTRIDE 204
#define PACK_UNITS (NREL * KTKG * NCOLP)

typedef __attribute__((ext_vector_type(8))) short bf16x8;
typedef __attribute__((ext_vector_type(4))) float f32x4;

__device__ __forceinline__ uint f2bf(float x) {
    __hip_bfloat16 h = __float2bfloat16(x);   // RNE
    return (uint)*reinterpret_cast<ushort*>(&h);
}
__device__ __forceinline__ float fast_tanh(float x) {
    const float xc = fminf(fmaxf(x, -20.f), 20.f);
    const float e  = __expf(2.f * xc);
    return 1.f - __fdividef(2.f, e + 1.f);
}

// ---------- Kernel 1: block 0 = sort + chunks + eid table; blocks 1.. = W pack ----------
__global__ __launch_bounds__(1024) void prep_kernel(
    const float* __restrict__ W, ushort* __restrict__ Wpk, int do_pack,
    const int* __restrict__ bi, int B, int nblk,
    int* __restrict__ perm, int* __restrict__ blk_r,
    int* __restrict__ blk_start, int* __restrict__ blk_cnt,
    int* __restrict__ eidArr)
{
    const int tid = threadIdx.x;

    if (blockIdx.x != 0) {
        if (!do_pack) return;
        const int u = (blockIdx.x - 1) * 1024 + tid;
        if (u >= PACK_UNITS) return;
        const int col  = u % NCOLP;
        const int rk   = u / NCOLP;
        const int ktkg = rk % KTKG;
        const int r    = rk / KTKG;
        const int k0   = ktkg * 8;
        uint4 pk = {0u, 0u, 0u, 0u};
        if (col < DDIM) {
            const float* base = W + (size_t)r * DDIM * DDIM + col;
            uint vv[8];
            #pragma unroll
            for (int j = 0; j < 8; ++j) {
                const int k = k0 + j;
                vv[j] = (k < DDIM) ? f2bf(base[(size_t)k * DDIM]) : 0u;  // coalesced per j
            }
            pk.x = vv[0] | (vv[1] << 16);
            pk.y = vv[2] | (vv[3] << 16);
            pk.z = vv[4] | (vv[5] << 16);
            pk.w = vv[6] | (vv[7] << 16);
        }
        *(uint4*)&Wpk[(size_t)u * 8] = pk;
        return;
    }

    // ---- block 0: counting sort + balanced chunk emission + eid table ----
    __shared__ int hist[NREL];
    __shared__ int offs[NREL];
    __shared__ int wsum[16], wsum2[16];
    const int lane = tid & 63;
    const int w    = tid >> 6;

    if (tid < NREL) hist[tid] = 0;
    __syncthreads();
    for (int i = tid; i < B; i += 1024)
        atomicAdd(&hist[bi[i * 3 + 1]], 1);
    __syncthreads();

    const int v  = (tid < NREL) ? hist[tid] : 0;
    const int v2 = (tid < NREL) ? (v + MAXE - 1) / MAXE : 0;
    int s = v, s2 = v2;
    #pragma unroll
    for (int off = 1; off < 64; off <<= 1) {
        const int u  = __shfl_up(s,  off, 64);
        const int u2 = __shfl_up(s2, off, 64);
        if (lane >= off) { s += u; s2 += u2; }
    }
    if (lane == 63) { wsum[w] = s; wsum2[w] = s2; }
    __syncthreads();
    int base = 0, base2 = 0;
    for (int i = 0; i < w; ++i) { base += wsum[i]; base2 += wsum2[i]; }
    const int my_off  = base  + s  - v;
    const int my_boff = base2 + s2 - v2;
    if (tid < NREL) offs[tid] = my_off;
    __syncthreads();

    for (int i = tid; i < nblk; i += 1024) blk_cnt[i] = 0;
    if (tid < NREL && v > 0) {
        const int nb = (v + MAXE - 1) / MAXE;
        const int cb = v / nb, ext = v - cb * nb;
        int pos = my_off;
        for (int j = 0; j < nb; ++j) {
            const int c = cb + (j < ext ? 1 : 0);
            blk_r[my_boff + j]     = tid;
            blk_start[my_boff + j] = pos;
            blk_cnt[my_boff + j]   = c;
            pos += c;
        }
    }
    __syncthreads();
    for (int i = tid; i < B; i += 1024) {
        const int pos = atomicAdd(&offs[bi[i * 3 + 1]], 1);
        perm[pos] = i;
    }
    __syncthreads();
    for (int p = tid; p < B; p += 1024) {
        const int b = perm[p];
        eidArr[2 * p]     = bi[3 * b + 0];   // head
        eidArr[2 * p + 1] = bi[3 * b + 2];   // tail
    }
}

// ---------- Kernel 2: MFMA monolith with register-pipelined B feed ----------
template <bool PACKED>
__global__ __launch_bounds__(NT) void spkbgat_mfma_kernel(
    const float*  __restrict__ ent,
    const float*  __restrict__ rel_emb,
    const float*  __restrict__ W,
    const ushort* __restrict__ Wpk,
    const float*  __restrict__ conv_w,
    const float*  __restrict__ conv_b,
    const float*  __restrict__ fc_w,
    const float*  __restrict__ fc_b,
    const int*    __restrict__ perm,
    const int*    __restrict__ blk_r,
    const int*    __restrict__ blk_start,
    const int*    __restrict__ blk_cnt,
    const int*    __restrict__ eidArr,
    int nblk,
    float*        __restrict__ out)
{
    __shared__ __align__(16) ushort Ash[KTKG * AROWS * 8];   // 7 KB fragment layout
    __shared__ __align__(16) float  Osh[AROWS][OSTRIDE];     // 13 KB tanh'd se/te
    __shared__ __align__(16) float4 rl4[D4];
    __shared__ __align__(16) float  cwb[CCH][4];             // {w0,w1,w2,b}

    const int tid  = threadIdx.x;
    const int w    = tid >> 6;
    const int lane = tid & 63;
    const int l16  = lane & 15;
    const int kg   = lane >> 4;

    // bijective XCD-chunked swizzle (same-relation chunks share an XCD L2)
    const int bid = blockIdx.x;
    const int q = nblk >> 3, rmd = nblk & 7;
    const int xcd = bid & 7, idx = bid >> 3;
    const int gidx = (xcd < rmd ? xcd * (q + 1) : rmd * (q + 1) + (xcd - rmd) * q) + idx;

    const int cnt = blk_cnt[gidx];
    if (cnt == 0) return;   // block-uniform: safe before barriers

    const int r     = blk_r[gidx];
    const int start = blk_start[gidx];
    const int rows  = 2 * cnt;

    // ---- small stages ----
    if (tid < CCH) {
        cwb[tid][0] = conv_w[tid * 3 + 0];
        cwb[tid][1] = conv_w[tid * 3 + 1];
        cwb[tid][2] = conv_w[tid * 3 + 2];
        cwb[tid][3] = conv_b[tid];
    }
    if (tid < D4) rl4[tid] = ((const float4*)rel_emb)[r * D4 + tid];

    // ---- A stage: 28 ktkg-groups x 16 A-rows -> one b128 LDS write per unit ----
    for (int u = tid; u < KTKG * AROWS; u += NT) {
        const int row  = u & (AROWS - 1);
        const int ktkg = u >> 4;
        uint4 pk = {0u, 0u, 0u, 0u};
        if (ktkg < 25 && row < rows) {               // 25*8 = 200 real k's
            const int eid = eidArr[2 * start + row]; // L1-resident (16 values)
            const float* xp = ent + (size_t)eid * DDIM + ktkg * 8;
            const float4 x0 = *(const float4*)xp;
            const float4 x1 = *(const float4*)(xp + 4);
            pk.x = f2bf(x0.x) | (f2bf(x0.y) << 16);
            pk.y = f2bf(x0.z) | (f2bf(x0.w) << 16);
            pk.z = f2bf(x1.x) | (f2bf(x1.y) << 16);
            pk.w = f2bf(x1.z) | (f2bf(x1.w) << 16);
        }
        *(uint4*)&Ash[u * 8] = pk;
    }
    __syncthreads();

    // ---- MFMA loop: A in regs (7 frags), B register double-buffered ----
    const int nslots = (w == 0) ? 4 : 3;
    const float*  __restrict__ Wr = W + (size_t)r * DDIM * DDIM;
    // per-slot base pointers into packed W; kt stride = 4*NCOLP*8 ushorts
    const ushort* __restrict__ Wp0 = Wpk + (size_t)r * KTKG * NCOLP * 8
                                   + ((size_t)kg * NCOLP) * 8 + (size_t)l16 * 8;

    bf16x8 a_frag[KT];
    #pragma unroll
    for (int kt = 0; kt < KT; ++kt)
        a_frag[kt] = *(const bf16x8*)&Ash[((kt * 4 + kg) * AROWS + l16) * 8];

    f32x4 acc[4];
    #pragma unroll
    for (int s = 0; s < 4; ++s) acc[s] = (f32x4){0.f, 0.f, 0.f, 0.f};

    if (PACKED) {
        bf16x8 bcur[4], bnxt[4];
        #pragma unroll
        for (int s = 0; s < 4; ++s)
            if (s < nslots)
                bcur[s] = *(const bf16x8*)(Wp0 + (size_t)(w + 4 * s) * 16 * 8);
        #pragma unroll
        for (int kt = 0; kt < KT; ++kt) {
            if (kt + 1 < KT) {
                const ushort* pn = Wp0 + (size_t)(kt + 1) * 4 * NCOLP * 8;
                #pragma unroll
                for (int s = 0; s < 4; ++s)
                    if (s < nslots)
                        bnxt[s] = *(const bf16x8*)(pn + (size_t)(w + 4 * s) * 16 * 8);
            }
            #pragma unroll
            for (int s = 0; s < 4; ++s)
                if (s < nslots)
                    acc[s] = __builtin_amdgcn_mfma_f32_16x16x32_bf16(
                        a_frag[kt], bcur[s], acc[s], 0, 0, 0);
            #pragma unroll
            for (int s = 0; s < 4; ++s)
                if (s < nslots) bcur[s] = bnxt[s];
        }
    } else {
        for (int kt = 0; kt < KT; ++kt) {
            const int k0b = (kt * 4 + kg) * 8;
            #pragma unroll
            for (int s = 0; s < 4; ++s) {
                if (s < nslots) {
                    const int col = (w + 4 * s) * 16 + l16;
                    bf16x8 bfr;
                    #pragma unroll
                    for (int j = 0; j < 8; ++j) {
                        const int k = k0b + j;
                        const float vv = (k < DDIM && col < DDIM) ? Wr[k * DDIM + col] : 0.f;
                        bfr[j] = (short)f2bf(vv);
                    }
                    acc[s] = __builtin_amdgcn_mfma_f32_16x16x32_bf16(
                        a_frag[kt], bfr, acc[s], 0, 0, 0);
                }
            }
        }
    }

    // ---- tanh + write se/te rows: D[row=kg*4+v][col=l16+16*(w+4s)] ----
    #pragma unroll
    for (int s = 0; s < 4; ++s) {
        if (s < nslots) {
            const int gcol = (w + 4 * s) * 16 + l16;
            if (gcol < DDIM) {
                #pragma unroll
                for (int v = 0; v < 4; ++v) {
                    const int grow = kg * 4 + v;
                    if (grow < rows)
                        Osh[grow][gcol] = fast_tanh(acc[s][v]);
                }
            }
        }
    }
    __syncthreads();

    // ---- epilogue: wave w owns elements {w, w+4}; lane owns a d4-slice ----
    float4 sa[2] = {{0,0,0,0}, {0,0,0,0}};
    if (lane < D4) {
        const float4 rv = rl4[lane];
        float4 se[2], te[2];
        #pragma unroll
        for (int s2 = 0; s2 < 2; ++s2) {
            const int e = w + 4 * s2;
            if (e < cnt) {
                se[s2] = *(const float4*)&Osh[2 * e][4 * lane];
                te[s2] = *(const float4*)&Osh[2 * e + 1][4 * lane];
            } else {
                se[s2] = (float4){0,0,0,0};
                te[s2] = (float4){0,0,0,0};
            }
        }
        for (int c = 0; c < CCH; ++c) {
            const float4 cw  = *(const float4*)&cwb[c][0];
            const float4 fc4 = ((const float4*)fc_w)[c * D4 + lane];   // L2-cached
            #pragma unroll
            for (int s2 = 0; s2 < 2; ++s2) {
                const float v0 = fmaf(cw.x, se[s2].x, fmaf(cw.y, rv.x, fmaf(cw.z, te[s2].x, cw.w)));
                const float v1 = fmaf(cw.x, se[s2].y, fmaf(cw.y, rv.y, fmaf(cw.z, te[s2].y, cw.w)));
                const float v2 = fmaf(cw.x, se[s2].z, fmaf(cw.y, rv.z, fmaf(cw.z, te[s2].z, cw.w)));
                const float v3 = fmaf(cw.x, se[s2].w, fmaf(cw.y, rv.w, fmaf(cw.z, te[s2].w, cw.w)));
                sa[s2].x = fmaf(fmaxf(v0, 0.f), fc4.x, sa[s2].x);
                sa[s2].y = fmaf(fmaxf(v1, 0.f), fc4.y, sa[s2].y);
                sa[s2].z = fmaf(fmaxf(v2, 0.f), fc4.z, sa[s2].z);
                sa[s2].w = fmaf(fmaxf(v3, 0.f), fc4.w, sa[s2].w);
            }
        }
    }
    #pragma unroll
    for (int s2 = 0; s2 < 2; ++s2) {
        float sum = (sa[s2].x + sa[s2].y) + (sa[s2].z + sa[s2].w);
        #pragma unroll
        for (int off = 32; off; off >>= 1)
            sum += __shfl_down(sum, off, 64);
        const int e = w + 4 * s2;
        if (lane == 0 && e < cnt)
            out[perm[start + e]] = sum + fc_b[0];
    }
}

extern "C" void kernel_launch(void* const* d_in, const int* in_sizes, int n_in,
                              void* d_out, int out_size, void* d_ws, size_t ws_size,
                              hipStream_t stream) {
    const int*   bi      = (const int*)  d_in[0];
    const float* ent     = (const float*)d_in[1];
    const float* rel_emb = (const float*)d_in[2];
    const float* W       = (const float*)d_in[3];
    const float* conv_w  = (const float*)d_in[4];
    const float* conv_b  = (const float*)d_in[5];
    const float* fc_w    = (const float*)d_in[6];
    const float* fc_b    = (const float*)d_in[7];
    float*       out     = (float*)d_out;

    const int B    = in_sizes[0] / 3;                  // 8192
    const int nblk = NREL + (B + MAXE - 1) / MAXE;     // 1261 worst-case chunks

    int* perm      = (int*)d_ws;                       // B
    int* blk_r     = perm + B;                         // nblk
    int* blk_start = blk_r + nblk;                     // nblk
    int* blk_cnt   = blk_start + nblk;                 // nblk
    int* eidArr    = blk_cnt + nblk;                   // 2B

    const size_t meta_bytes = (size_t)(3 * B + 3 * nblk) * sizeof(int);
    const size_t pk_off     = (meta_bytes + 255) & ~(size_t)255;
    const size_t need       = pk_off + (size_t)PACK_UNITS * 16;
    const bool   use_packed = (ws_size >= need);
    ushort* Wpk = (ushort*)((char*)d_ws + pk_off);

    const int prep_blocks = 1 + (PACK_UNITS + 1023) / 1024;
    prep_kernel<<<prep_blocks, 1024, 0, stream>>>(
        W, Wpk, use_packed ? 1 : 0, bi, B, nblk,
        perm, blk_r, blk_start, blk_cnt, eidArr);

    if (use_packed) {
        spkbgat_mfma_kernel<true><<<nblk, NT, 0, stream>>>(
            ent, rel_emb, W, Wpk, conv_w, conv_b, fc_w, fc_b,
            perm, blk_r, blk_start, blk_cnt, eidArr, nblk, out);
    } else {
        spkbgat_mfma_kernel<false><<<nblk, NT, 0, stream>>>(
            ent, rel_emb, W, Wpk, conv_w, conv_b, fc_w, fc_b,
            perm, blk_r, blk_start, blk_cnt, eidArr, nblk, out);
    }
}

// Round 11
// 53.587 us; speedup vs baseline: 1.1754x; 1.0917x over previous
//
#include <hip/hip_runtime.h>
#include <hip/hip_bf16.h>
#include <math.h>

#define DDIM 200
#define D4   50
#define CCH  50
#define NREL 237
#define MAXE 8           // elements per chunk
#define AROWS 16         // M-tile rows = 2*MAXE
#define NT   256
#define KT   7           // K tiles of 32 -> 224 (200 real, zero-padded)
#define KTKG 28          // (kt,kg) pairs: k0 = ktkg*8
#define NCOLP 208        // padded col count in packed W
#define OSTRIDE 204
#define PACK_UNITS (NREL * KTKG * NCOLP)

typedef __attribute__((ext_vector_type(8))) short bf16x8;
typedef __attribute__((ext_vector_type(4))) float f32x4;

__device__ __forceinline__ uint f2bf(float x) {
    __hip_bfloat16 h = __float2bfloat16(x);   // RNE
    return (uint)*reinterpret_cast<ushort*>(&h);
}
__device__ __forceinline__ float fast_tanh(float x) {
    const float xc = fminf(fmaxf(x, -20.f), 20.f);
    const float e  = __expf(2.f * xc);
    return 1.f - __fdividef(2.f, e + 1.f);
}

// ---------- Kernel 1: block 0 = sort+chunks+eid; blocks 1..237*7 = vectorized W pack ----------
__global__ __launch_bounds__(1024) void prep_kernel(
    const float* __restrict__ W, ushort* __restrict__ Wpk, int do_pack,
    const int* __restrict__ bi, int B, int nblk,
    int* __restrict__ perm, int* __restrict__ blk_r,
    int* __restrict__ blk_start, int* __restrict__ blk_cnt,
    int* __restrict__ eidArr)
{
    __shared__ __align__(16) float Wlds[32][DDIM];   // 25.6 KB pack staging
    __shared__ int hist[NREL];
    __shared__ int offs[NREL];
    __shared__ int wsum[16], wsum2[16];

    const int tid = threadIdx.x;

    if (blockIdx.x != 0) {
        // ---- pack: block handles (r, kt): 32 k-rows x 200 cols -> 4 ktkg x 208 frags ----
        if (!do_pack) return;
        const int blk = blockIdx.x - 1;
        const int r   = blk / KT;
        const int kt  = blk - r * KT;
        const int k0  = kt * 32;

        // stage slab: coalesced float4 reads (zero-fill padded k rows)
        for (int i = tid; i < 32 * D4; i += 1024) {
            const int krow = i / D4;
            const int c4   = i - krow * D4;
            const int gk   = k0 + krow;
            float4 v = {0.f, 0.f, 0.f, 0.f};
            if (gk < DDIM)
                v = *(const float4*)(W + ((size_t)r * DDIM + gk) * DDIM + 4 * c4);
            *(float4*)&Wlds[krow][4 * c4] = v;
        }
        __syncthreads();

        // assemble fragments: (kg, col) -> 8 bf16 from LDS column, contiguous 16B write
        for (int u = tid; u < 4 * NCOLP; u += 1024) {
            const int kg  = u / NCOLP;
            const int col = u - kg * NCOLP;
            uint4 pk = {0u, 0u, 0u, 0u};
            if (col < DDIM) {
                uint vv[8];
                #pragma unroll
                for (int j = 0; j < 8; ++j)
                    vv[j] = f2bf(Wlds[kg * 8 + j][col]);
                pk.x = vv[0] | (vv[1] << 16);
                pk.y = vv[2] | (vv[3] << 16);
                pk.z = vv[4] | (vv[5] << 16);
                pk.w = vv[6] | (vv[7] << 16);
            }
            const size_t unit = ((size_t)r * KTKG + kt * 4 + kg) * NCOLP + col;
            *(uint4*)&Wpk[unit * 8] = pk;
        }
        return;
    }

    // ---- block 0: counting sort + balanced chunk emission + fused eid scatter ----
    const int lane = tid & 63;
    const int w    = tid >> 6;

    if (tid < NREL) hist[tid] = 0;
    __syncthreads();
    for (int i = tid; i < B; i += 1024)
        atomicAdd(&hist[bi[i * 3 + 1]], 1);
    __syncthreads();

    const int v  = (tid < NREL) ? hist[tid] : 0;
    const int v2 = (tid < NREL) ? (v + MAXE - 1) / MAXE : 0;
    int s = v, s2 = v2;
    #pragma unroll
    for (int off = 1; off < 64; off <<= 1) {
        const int u  = __shfl_up(s,  off, 64);
        const int u2 = __shfl_up(s2, off, 64);
        if (lane >= off) { s += u; s2 += u2; }
    }
    if (lane == 63) { wsum[w] = s; wsum2[w] = s2; }
    __syncthreads();
    int base = 0, base2 = 0;
    for (int i = 0; i < w; ++i) { base += wsum[i]; base2 += wsum2[i]; }
    const int my_off  = base  + s  - v;
    const int my_boff = base2 + s2 - v2;
    if (tid < NREL) offs[tid] = my_off;
    __syncthreads();

    for (int i = tid; i < nblk; i += 1024) blk_cnt[i] = 0;
    if (tid < NREL && v > 0) {
        const int nb = (v + MAXE - 1) / MAXE;
        const int cb = v / nb, ext = v - cb * nb;
        int pos = my_off;
        for (int j = 0; j < nb; ++j) {
            const int c = cb + (j < ext ? 1 : 0);
            blk_r[my_boff + j]     = tid;
            blk_start[my_boff + j] = pos;
            blk_cnt[my_boff + j]   = c;
            pos += c;
        }
    }
    __syncthreads();
    // scatter + eid table in one pass
    for (int i = tid; i < B; i += 1024) {
        const int pos = atomicAdd(&offs[bi[i * 3 + 1]], 1);
        perm[pos] = i;
        eidArr[2 * pos]     = bi[3 * i + 0];   // head
        eidArr[2 * pos + 1] = bi[3 * i + 2];   // tail
    }
}

// ---------- Kernel 2: MFMA monolith with register-pipelined B feed ----------
template <bool PACKED>
__global__ __launch_bounds__(NT) void spkbgat_mfma_kernel(
    const float*  __restrict__ ent,
    const float*  __restrict__ rel_emb,
    const float*  __restrict__ W,
    const ushort* __restrict__ Wpk,
    const float*  __restrict__ conv_w,
    const float*  __restrict__ conv_b,
    const float*  __restrict__ fc_w,
    const float*  __restrict__ fc_b,
    const int*    __restrict__ perm,
    const int*    __restrict__ blk_r,
    const int*    __restrict__ blk_start,
    const int*    __restrict__ blk_cnt,
    const int*    __restrict__ eidArr,
    int nblk,
    float*        __restrict__ out)
{
    __shared__ __align__(16) ushort Ash[KTKG * AROWS * 8];   // 7 KB fragment layout
    __shared__ __align__(16) float  Osh[AROWS][OSTRIDE];     // 13 KB tanh'd se/te
    __shared__ __align__(16) float4 rl4[D4];
    __shared__ __align__(16) float  cwb[CCH][4];             // {w0,w1,w2,b}

    const int tid  = threadIdx.x;
    const int w    = tid >> 6;
    const int lane = tid & 63;
    const int l16  = lane & 15;
    const int kg   = lane >> 4;

    // bijective XCD-chunked swizzle (same-relation chunks share an XCD L2)
    const int bid = blockIdx.x;
    const int q = nblk >> 3, rmd = nblk & 7;
    const int xcd = bid & 7, idx = bid >> 3;
    const int gidx = (xcd < rmd ? xcd * (q + 1) : rmd * (q + 1) + (xcd - rmd) * q) + idx;

    const int cnt = blk_cnt[gidx];
    if (cnt == 0) return;   // block-uniform: safe before barriers

    const int r     = blk_r[gidx];
    const int start = blk_start[gidx];
    const int rows  = 2 * cnt;

    // ---- small stages ----
    if (tid < CCH) {
        cwb[tid][0] = conv_w[tid * 3 + 0];
        cwb[tid][1] = conv_w[tid * 3 + 1];
        cwb[tid][2] = conv_w[tid * 3 + 2];
        cwb[tid][3] = conv_b[tid];
    }
    if (tid < D4) rl4[tid] = ((const float4*)rel_emb)[r * D4 + tid];

    // ---- A stage: 28 ktkg-groups x 16 A-rows -> one b128 LDS write per unit ----
    for (int u = tid; u < KTKG * AROWS; u += NT) {
        const int row  = u & (AROWS - 1);
        const int ktkg = u >> 4;
        uint4 pk = {0u, 0u, 0u, 0u};
        if (ktkg < 25 && row < rows) {               // 25*8 = 200 real k's
            const int eid = eidArr[2 * start + row]; // L1-resident (16 values)
            const float* xp = ent + (size_t)eid * DDIM + ktkg * 8;
            const float4 x0 = *(const float4*)xp;
            const float4 x1 = *(const float4*)(xp + 4);
            pk.x = f2bf(x0.x) | (f2bf(x0.y) << 16);
            pk.y = f2bf(x0.z) | (f2bf(x0.w) << 16);
            pk.z = f2bf(x1.x) | (f2bf(x1.y) << 16);
            pk.w = f2bf(x1.z) | (f2bf(x1.w) << 16);
        }
        *(uint4*)&Ash[u * 8] = pk;
    }
    __syncthreads();

    // ---- MFMA loop: A in regs (7 frags), B register double-buffered ----
    const int nslots = (w == 0) ? 4 : 3;
    const float*  __restrict__ Wr = W + (size_t)r * DDIM * DDIM;
    const ushort* __restrict__ Wp0 = Wpk + (size_t)r * KTKG * NCOLP * 8
                                   + ((size_t)kg * NCOLP) * 8 + (size_t)l16 * 8;

    bf16x8 a_frag[KT];
    #pragma unroll
    for (int kt = 0; kt < KT; ++kt)
        a_frag[kt] = *(const bf16x8*)&Ash[((kt * 4 + kg) * AROWS + l16) * 8];

    f32x4 acc[4];
    #pragma unroll
    for (int s = 0; s < 4; ++s) acc[s] = (f32x4){0.f, 0.f, 0.f, 0.f};

    if (PACKED) {
        bf16x8 bcur[4], bnxt[4];
        #pragma unroll
        for (int s = 0; s < 4; ++s)
            if (s < nslots)
                bcur[s] = *(const bf16x8*)(Wp0 + (size_t)(w + 4 * s) * 16 * 8);
        #pragma unroll
        for (int kt = 0; kt < KT; ++kt) {
            if (kt + 1 < KT) {
                const ushort* pn = Wp0 + (size_t)(kt + 1) * 4 * NCOLP * 8;
                #pragma unroll
                for (int s = 0; s < 4; ++s)
                    if (s < nslots)
                        bnxt[s] = *(const bf16x8*)(pn + (size_t)(w + 4 * s) * 16 * 8);
            }
            #pragma unroll
            for (int s = 0; s < 4; ++s)
                if (s < nslots)
                    acc[s] = __builtin_amdgcn_mfma_f32_16x16x32_bf16(
                        a_frag[kt], bcur[s], acc[s], 0, 0, 0);
            #pragma unroll
            for (int s = 0; s < 4; ++s)
                if (s < nslots) bcur[s] = bnxt[s];
        }
    } else {
        for (int kt = 0; kt < KT; ++kt) {
            const int k0b = (kt * 4 + kg) * 8;
            #pragma unroll
            for (int s = 0; s < 4; ++s) {
                if (s < nslots) {
                    const int col = (w + 4 * s) * 16 + l16;
                    bf16x8 bfr;
                    #pragma unroll
                    for (int j = 0; j < 8; ++j) {
                        const int k = k0b + j;
                        const float vv = (k < DDIM && col < DDIM) ? Wr[k * DDIM + col] : 0.f;
                        bfr[j] = (short)f2bf(vv);
                    }
                    acc[s] = __builtin_amdgcn_mfma_f32_16x16x32_bf16(
                        a_frag[kt], bfr, acc[s], 0, 0, 0);
                }
            }
        }
    }

    // ---- tanh + write se/te rows: D[row=kg*4+v][col=l16+16*(w+4s)] ----
    #pragma unroll
    for (int s = 0; s < 4; ++s) {
        if (s < nslots) {
            const int gcol = (w + 4 * s) * 16 + l16;
            if (gcol < DDIM) {
                #pragma unroll
                for (int v = 0; v < 4; ++v) {
                    const int grow = kg * 4 + v;
                    if (grow < rows)
                        Osh[grow][gcol] = fast_tanh(acc[s][v]);
                }
            }
        }
    }
    __syncthreads();

    // ---- epilogue: wave w owns elements {w, w+4}; lane owns a d4-slice ----
    float4 sa[2] = {{0,0,0,0}, {0,0,0,0}};
    if (lane < D4) {
        const float4 rv = rl4[lane];
        float4 se[2], te[2];
        #pragma unroll
        for (int s2 = 0; s2 < 2; ++s2) {
            const int e = w + 4 * s2;
            if (e < cnt) {
                se[s2] = *(const float4*)&Osh[2 * e][4 * lane];
                te[s2] = *(const float4*)&Osh[2 * e + 1][4 * lane];
            } else {
                se[s2] = (float4){0,0,0,0};
                te[s2] = (float4){0,0,0,0};
            }
        }
        for (int c = 0; c < CCH; ++c) {
            const float4 cw  = *(const float4*)&cwb[c][0];
            const float4 fc4 = ((const float4*)fc_w)[c * D4 + lane];   // L2-cached
            #pragma unroll
            for (int s2 = 0; s2 < 2; ++s2) {
                const float v0 = fmaf(cw.x, se[s2].x, fmaf(cw.y, rv.x, fmaf(cw.z, te[s2].x, cw.w)));
                const float v1 = fmaf(cw.x, se[s2].y, fmaf(cw.y, rv.y, fmaf(cw.z, te[s2].y, cw.w)));
                const float v2 = fmaf(cw.x, se[s2].z, fmaf(cw.y, rv.z, fmaf(cw.z, te[s2].z, cw.w)));
                const float v3 = fmaf(cw.x, se[s2].w, fmaf(cw.y, rv.w, fmaf(cw.z, te[s2].w, cw.w)));
                sa[s2].x = fmaf(fmaxf(v0, 0.f), fc4.x, sa[s2].x);
                sa[s2].y = fmaf(fmaxf(v1, 0.f), fc4.y, sa[s2].y);
                sa[s2].z = fmaf(fmaxf(v2, 0.f), fc4.z, sa[s2].z);
                sa[s2].w = fmaf(fmaxf(v3, 0.f), fc4.w, sa[s2].w);
            }
        }
    }
    #pragma unroll
    for (int s2 = 0; s2 < 2; ++s2) {
        float sum = (sa[s2].x + sa[s2].y) + (sa[s2].z + sa[s2].w);
        #pragma unroll
        for (int off = 32; off; off >>= 1)
            sum += __shfl_down(sum, off, 64);
        const int e = w + 4 * s2;
        if (lane == 0 && e < cnt)
            out[perm[start + e]] = sum + fc_b[0];
    }
}

extern "C" void kernel_launch(void* const* d_in, const int* in_sizes, int n_in,
                              void* d_out, int out_size, void* d_ws, size_t ws_size,
                              hipStream_t stream) {
    const int*   bi      = (const int*)  d_in[0];
    const float* ent     = (const float*)d_in[1];
    const float* rel_emb = (const float*)d_in[2];
    const float* W       = (const float*)d_in[3];
    const float* conv_w  = (const float*)d_in[4];
    const float* conv_b  = (const float*)d_in[5];
    const float* fc_w    = (const float*)d_in[6];
    const float* fc_b    = (const float*)d_in[7];
    float*       out     = (float*)d_out;

    const int B    = in_sizes[0] / 3;                  // 8192
    const int nblk = NREL + (B + MAXE - 1) / MAXE;     // 1261 worst-case chunks

    int* perm      = (int*)d_ws;                       // B
    int* blk_r     = perm + B;                         // nblk
    int* blk_start = blk_r + nblk;                     // nblk
    int* blk_cnt   = blk_start + nblk;                 // nblk
    int* eidArr    = blk_cnt + nblk;                   // 2B

    const size_t meta_bytes = (size_t)(3 * B + 3 * nblk) * sizeof(int);
    const size_t pk_off     = (meta_bytes + 255) & ~(size_t)255;
    const size_t need       = pk_off + (size_t)PACK_UNITS * 16;
    const bool   use_packed = (ws_size >= need);
    ushort* Wpk = (ushort*)((char*)d_ws + pk_off);

    const int prep_blocks = 1 + NREL * KT;   // block 0 = sort; 1659 pack blocks
    prep_kernel<<<prep_blocks, 1024, 0, stream>>>(
        W, Wpk, use_packed ? 1 : 0, bi, B, nblk,
        perm, blk_r, blk_start, blk_cnt, eidArr);

    if (use_packed) {
        spkbgat_mfma_kernel<true><<<nblk, NT, 0, stream>>>(
            ent, rel_emb, W, Wpk, conv_w, conv_b, fc_w, fc_b,
            perm, blk_r, blk_start, blk_cnt, eidArr, nblk, out);
    } else {
        spkbgat_mfma_kernel<false><<<nblk, NT, 0, stream>>>(
            ent, rel_emb, W, Wpk, conv_w, conv_b, fc_w, fc_b,
            perm, blk_r, blk_start, blk_cnt, eidArr, nblk, out);
    }
}